// Round 19
// baseline (384.548 us; speedup 1.0000x reference)
//
#include <hip/hip_runtime.h>
#include <math.h>

#define NN 10000
#define NE 160000
#define NG 64
#define DIM 32
#define CAP 96   // per-node edge slot capacity (max degree ~40 at Binomial(160K,1e-4))

typedef __attribute__((ext_vector_type(8))) short bf16x8;
typedef __attribute__((ext_vector_type(4))) float f32x4;

__device__ __forceinline__ float sigmoidf_(float x) { return 1.f / (1.f + expf(-x)); }

// round-to-nearest-even fp32 -> bf16 bits
__device__ __forceinline__ unsigned short f2bf(float x) {
    unsigned u = __float_as_uint(x);
    u += 0x7FFF + ((u >> 16) & 1);
    return (unsigned short)(u >> 16);
}
__device__ __forceinline__ float bf2f(unsigned short b) {
    return __uint_as_float(((unsigned)b) << 16);
}

// ---------------------------------------------------------------- fused setup + fill
//   b<512:        W2 -> B-fragment bf16 hi/lo planes (linear w2 read, coalesced)
//   b<1762:       lin0 + relu
//   b==1762:      gstart binary search
//   b>=1763:      direct-slot edge bucketing (625 blocks)
__global__ void k_setup(const float* __restrict__ w2, unsigned short* __restrict__ w2f,
                        const float* __restrict__ x, const float* __restrict__ lw,
                        const float* __restrict__ lb, float* __restrict__ out,
                        const int* __restrict__ batch, int* __restrict__ gstart,
                        const int* __restrict__ ei, const float* __restrict__ ea,
                        int* __restrict__ cursor,
                        int* __restrict__ srt_src, float* __restrict__ srt_ea) {
    int b = blockIdx.x, t = threadIdx.x;
    if (b < 512) {
        int tid = b * 256 + t;                        // linear w2 index (coalesced)
        int h = tid >> 10, rem = tid & 1023, i = rem >> 5, n = rem & 31;
        float v = w2[tid];
        unsigned short hi = f2bf(v);
        unsigned short lo = f2bf(v - bf2f(hi));
        int s = h >> 5, hm = h & 31, q = hm >> 3, j = hm & 7;
        int tile = n >> 4, nn = n & 15, lane = q * 16 + nn;
        int c = (i * 4 + s) * 2 + tile;
        w2f[(c * 2 + 0) * 512 + lane * 8 + j] = hi;
        w2f[(c * 2 + 1) * 512 + lane * 8 + j] = lo;
    } else if (b < 1762) {
        int idx = (b - 512) * 256 + t;               // < NN*DIM
        int n = idx >> 5, d = idx & 31;
        out[idx] = fmaxf(x[n] * lw[d] + lb[d], 0.f);
    } else if (b == 1762) {
        if (t <= NG) {
            int g = t, lo = 0, hi = NN;
            while (lo < hi) { int mid = (lo + hi) >> 1; if (batch[mid] < g) lo = mid + 1; else hi = mid; }
            gstart[g] = lo;
        }
    } else {
        int e = (b - 1763) * 256 + t;
        if (e < NE) {
            int d = ei[NE + e];
            int p = atomicAdd(&cursor[d], 1);
            int pos = d * CAP + p;
            srt_src[pos] = ei[e];
            srt_ea[2 * pos]     = ea[2 * e];
            srt_ea[2 * pos + 1] = ea[2 * e + 1];
        }
    }
}

// ---------------------------------------------------------------- NNConv + GRU fused
// 512 threads = 8 waves = 4 nodes, TWO waves per node (h-split: wave owns 64 of
// 128 h) -> Racc is 32 regs, true usage ~74 < the (512,6) 85-reg budget ->
// 24 waves/CU (was 16). Rows come via the scalar pipe (duplication across the
// wave pair is cheap, L2-cached) — this is R5's split redone post-R7.
// Contraction via MFMA 16x16x32 bf16, bf16x3 split precision, unchanged wave->
// i-row mapping (R routed through LDS); M = 4 real nodes of 16.
#define NS 1040
#define PS 4160   // 4 nodes x NS (one bf16 plane)
__global__ __launch_bounds__(512, 6) void k_conv_gru(
    const int* __restrict__ cursor, const int* __restrict__ srt_src,
    const float* __restrict__ srt_ea,
    const float* __restrict__ w1, const float* __restrict__ b1,
    const unsigned short* __restrict__ w2f, const float* __restrict__ b2,
    const float* __restrict__ out_old,
    float* __restrict__ Sg,
    const float* __restrict__ root, const float* __restrict__ cbias,
    const float* __restrict__ wih, const float* __restrict__ whh,
    const float* __restrict__ bih, const float* __restrict__ bhh,
    float* __restrict__ out_new)
{
    __shared__ __align__(16) unsigned short RB[2 * PS];   // hi plane + lo plane (~16.6 KB)
    int t = threadIdx.x;
    int wave = t >> 6, lane = t & 63;
    int n0 = blockIdx.x * 4;
    int node = n0 + (wave >> 1);        // wave pair owns one node
    int hoff = (wave & 1) * 64;         // this wave's h-half

    // ---------------- edge phase (2 independent chains per iteration) ----------------
    float Racc[32];
    #pragma unroll
    for (int i = 0; i < 32; ++i) Racc[i] = 0.f;
    float sacc = 0.f;

    int h = hoff + lane;
    float w1a = w1[h], w1c = w1[128 + h], bb = b1[h];

    int rs = node * CAP;
    int re = rs + cursor[node];
    const float2* eap = (const float2*)srt_ea;

    int p = rs;
    for (; p + 1 < re; p += 2) {
        int s0 = __builtin_amdgcn_readfirstlane(srt_src[p]);
        int s1 = __builtin_amdgcn_readfirstlane(srt_src[p + 1]);
        float2 a0 = eap[p];
        float2 a1 = eap[p + 1];
        const float* o0 = out_old + s0 * DIM;     // uniform -> s_load
        const float* o1 = out_old + s1 * DIM;     // independent chain
        float rA = fmaxf(a0.x * w1a + a0.y * w1c + bb, 0.f);
        float rB = fmaxf(a1.x * w1a + a1.y * w1c + bb, 0.f);
        #pragma unroll
        for (int q = 0; q < 32; ++q) Racc[q] += rA * o0[q];
        #pragma unroll
        for (int q = 0; q < 32; ++q) Racc[q] += rB * o1[q];
        if (hoff == 0 && lane < DIM) sacc += o0[lane] + o1[lane];
    }
    if (p < re) {                                  // tail edge
        int s0 = __builtin_amdgcn_readfirstlane(srt_src[p]);
        float2 a0 = eap[p];
        const float* o0 = out_old + s0 * DIM;
        float rA = fmaxf(a0.x * w1a + a0.y * w1c + bb, 0.f);
        #pragma unroll
        for (int q = 0; q < 32; ++q) Racc[q] += rA * o0[q];
        if (hoff == 0 && lane < DIM) sacc += o0[lane];
    }
    if (hoff == 0 && lane < DIM) Sg[node * DIM + lane] = sacc;

    // ---------------- MFMA contraction: 4 i-passes of 8 ----------------
    int quad = lane >> 4;
    int mm = lane & 3;                  // A rows 4..15 dup of 0..3 (unread in D)
    unsigned aoff = (unsigned)(mm * NS + wave * 128 + quad * 8);
    f32x4 acc0 = {0.f, 0.f, 0.f, 0.f};
    f32x4 acc1 = {0.f, 0.f, 0.f, 0.f};

    unsigned short* Hw = RB + (wave >> 1) * NS;    // this wave pair's node slice
    unsigned short* Lw = RB + PS + (wave >> 1) * NS;

    #pragma unroll
    for (int pass = 0; pass < 4; ++pass) {
        if (pass) __syncthreads();                 // prior pass's reads done
        #pragma unroll
        for (int li = 0; li < 8; ++li) {
            float v0 = Racc[pass * 8 + li];        // h = hoff + lane
            unsigned short h0 = f2bf(v0);
            unsigned short l0 = f2bf(v0 - bf2f(h0));
            Hw[li * 128 + hoff + lane] = h0;
            Lw[li * 128 + hoff + lane] = l0;
        }
        __syncthreads();
        int ig = pass * 8 + wave;                  // global i-row this wave covers
        #pragma unroll
        for (int s = 0; s < 4; ++s) {
            bf16x8 ah = *(const bf16x8*)(RB + aoff + s * 32);
            bf16x8 al = *(const bf16x8*)(RB + PS + aoff + s * 32);
            const unsigned short* bp = w2f + (unsigned)((ig * 4 + s) * 2048 + lane * 8);
            bf16x8 bh0 = *(const bf16x8*)(bp);
            bf16x8 bl0 = *(const bf16x8*)(bp + 512);
            bf16x8 bh1 = *(const bf16x8*)(bp + 1024);
            bf16x8 bl1 = *(const bf16x8*)(bp + 1536);
            acc0 = __builtin_amdgcn_mfma_f32_16x16x32_bf16(ah, bh0, acc0, 0, 0, 0);
            acc0 = __builtin_amdgcn_mfma_f32_16x16x32_bf16(ah, bl0, acc0, 0, 0, 0);
            acc0 = __builtin_amdgcn_mfma_f32_16x16x32_bf16(al, bh0, acc0, 0, 0, 0);
            acc1 = __builtin_amdgcn_mfma_f32_16x16x32_bf16(ah, bh1, acc1, 0, 0, 0);
            acc1 = __builtin_amdgcn_mfma_f32_16x16x32_bf16(ah, bl1, acc1, 0, 0, 0);
            acc1 = __builtin_amdgcn_mfma_f32_16x16x32_bf16(al, bh1, acc1, 0, 0, 0);
        }
    }
    __syncthreads();                               // all RB reads complete

    // ---- K-partial reduction through LDS (reuse RB as float area) ----
    float* part = (float*)RB;                      // 16 tiles x 64 lanes x 4 = 16 KB
    #pragma unroll
    for (int r = 0; r < 4; ++r) {
        part[((wave * 2 + 0) * 64 + lane) * 4 + r] = acc0[r];
        part[((wave * 2 + 1) * 64 + lane) * 4 + r] = acc1[r];
    }
    __syncthreads();

    // ---------------- fused GRU epilogue (threads 0..127: 4 nodes x 32 dims) ----------------
    if (t < 128) {
        int nb = t >> 5, d = t & 31;
        int nn_ = n0 + nb;
        int base = t & 32;                          // shfl base within wave
        // C/D layout: row=(lane>>4)*4+reg, col=lane&15; node nb sits at row=nb
        // (lane>>4 == 0, reg = nb), col = d&15, tile = d>>4
        int tile = d >> 4, col = d & 15;
        float aggv = 0.f;
        #pragma unroll
        for (int wv = 0; wv < 8; ++wv)
            aggv += part[((wv * 2 + tile) * 64 + col) * 4 + nb];

        float bt = 0.f;
        #pragma unroll 8
        for (int i = 0; i < DIM; ++i) bt += Sg[nn_ * DIM + i] * b2[i * DIM + d];
        int cdeg = cursor[nn_];
        float degf = (float)(cdeg > 0 ? cdeg : 1);
        aggv = (aggv + bt) / degf;

        float x = out_old[nn_ * DIM + d];           // h_old[d]
        float rootsum = 0.f;
        #pragma unroll 8
        for (int k = 0; k < DIM; ++k)
            rootsum += __shfl(x, base + k) * root[k * DIM + d];
        float m = fmaxf(aggv + rootsum + cbias[d], 0.f);

        float gir = bih[d], giz = bih[DIM + d], gin = bih[2 * DIM + d];
        float ghr = bhh[d], ghz = bhh[DIM + d], ghn = bhh[2 * DIM + d];
        #pragma unroll 4
        for (int k = 0; k < DIM; ++k) {
            float mk = __shfl(m, base + k);
            float hk = __shfl(x, base + k);
            gir += mk * wih[k * 96 + d];
            giz += mk * wih[k * 96 + DIM + d];
            gin += mk * wih[k * 96 + 2 * DIM + d];
            ghr += hk * whh[k * 96 + d];
            ghz += hk * whh[k * 96 + DIM + d];
            ghn += hk * whh[k * 96 + 2 * DIM + d];
        }
        float rg = sigmoidf_(gir + ghr);
        float zg = sigmoidf_(giz + ghz);
        float ng = tanhf(gin + rg * ghn);
        out_new[nn_ * DIM + d] = (1.f - zg) * ng + zg * x;
    }
}

// ---------------------------------------------------------------- Set2Set + head
__global__ __launch_bounds__(256) void k_set2set(
    const float* __restrict__ out, const int* __restrict__ gstart,
    const float* __restrict__ wih, const float* __restrict__ whh,
    const float* __restrict__ bih, const float* __restrict__ bhh,
    const float* __restrict__ l1w, const float* __restrict__ l1b,
    const float* __restrict__ l2w, const float* __restrict__ l2b,
    float* __restrict__ ebuf, float* __restrict__ y)
{
    __shared__ float swih[64 * 128];   // 32 KB
    __shared__ float swhh[32 * 128];   // 16 KB
    __shared__ float sq[2 * DIM];
    __shared__ float shh[DIM], scc[DIM];
    __shared__ float sgates[4 * DIM];
    __shared__ float sacc[8][DIM];
    __shared__ float sredA[4], sredB[4];

    int g = blockIdx.x, t = threadIdx.x;
    {
        const float4* wv = (const float4*)wih;   float4* sv = (float4*)swih;
        for (int i = t; i < 2048; i += 256) sv[i] = wv[i];
        const float4* wv2 = (const float4*)whh;  float4* sv2 = (float4*)swhh;
        for (int i = t; i < 1024; i += 256) sv2[i] = wv2[i];
    }
    if (t < 2 * DIM) sq[t] = 0.f;
    if (t < DIM) { shh[t] = 0.f; scc[t] = 0.f; }
    int ns = gstart[g], ne = gstart[g + 1];
    __syncthreads();

    for (int step = 0; step < 3; ++step) {
        if (t < 128) {
            float acc = bih[t] + bhh[t];
            #pragma unroll 8
            for (int k = 0; k < 2 * DIM; ++k) acc += sq[k] * swih[k * 128 + t];
            #pragma unroll 8
            for (int k = 0; k < DIM; ++k)     acc += shh[k] * swhh[k * 128 + t];
            sgates[t] = acc;
        }
        __syncthreads();
        if (t < DIM) {
            float ig = sigmoidf_(sgates[t]);
            float fg = sigmoidf_(sgates[DIM + t]);
            float gg = tanhf(sgates[2 * DIM + t]);
            float og = sigmoidf_(sgates[3 * DIM + t]);
            float c_new = fg * scc[t] + ig * gg;
            float h_new = og * tanhf(c_new);
            scc[t] = c_new;
            shh[t] = h_new;
            sq[t] = h_new;
        }
        __syncthreads();

        float lmax = -3.0e38f;
        for (int n = ns + t; n < ne; n += 256) {
            const float4* orow = (const float4*)(out + n * DIM);
            float e = 0.f;
            #pragma unroll
            for (int q = 0; q < 8; ++q) {
                float4 o4 = orow[q];
                e += o4.x * shh[4 * q] + o4.y * shh[4 * q + 1]
                   + o4.z * shh[4 * q + 2] + o4.w * shh[4 * q + 3];
            }
            ebuf[n] = e;
            lmax = fmaxf(lmax, e);
        }
        #pragma unroll
        for (int s = 1; s < 64; s <<= 1) lmax = fmaxf(lmax, __shfl_xor(lmax, s));
        if ((t & 63) == 0) sredA[t >> 6] = lmax;
        __syncthreads();
        float M = fmaxf(fmaxf(sredA[0], sredA[1]), fmaxf(sredA[2], sredA[3]));

        float lsum = 0.f;
        for (int n = ns + t; n < ne; n += 256) {
            float v = expf(ebuf[n] - M);
            ebuf[n] = v;
            lsum += v;
        }
        #pragma unroll
        for (int s = 1; s < 64; s <<= 1) lsum += __shfl_xor(lsum, s);
        if ((t & 63) == 0) sredB[t >> 6] = lsum;
        __syncthreads();
        float S = sredB[0] + sredB[1] + sredB[2] + sredB[3];
        float inv = (S > 0.f) ? 1.f / S : 0.f;

        int stp = t >> 5, d = t & 31;
        float racc = 0.f;
        for (int n = ns + stp; n < ne; n += 8)
            racc += ebuf[n] * out[n * DIM + d];
        sacc[stp][d] = racc;
        __syncthreads();
        if (t < DIM) {
            float r = 0.f;
            #pragma unroll
            for (int s = 0; s < 8; ++s) r += sacc[s][t];
            sq[DIM + t] = r * inv;
        }
        __syncthreads();
    }

    if (t < DIM) {
        float h = l1b[t];
        #pragma unroll 8
        for (int k = 0; k < 2 * DIM; ++k) h += sq[k] * l1w[k * DIM + t];
        float v = fmaxf(h, 0.f) * l2w[t];
        #pragma unroll
        for (int s = 1; s < 32; s <<= 1) v += __shfl_xor(v, s);
        if (t == 0) y[g] = v + l2b[0];
    }
}

// ---------------------------------------------------------------- launch
extern "C" void kernel_launch(void* const* d_in, const int* in_sizes, int n_in,
                              void* d_out, int out_size, void* d_ws, size_t ws_size,
                              hipStream_t stream) {
    const float* x         = (const float*)d_in[0];
    const float* edge_attr = (const float*)d_in[1];
    const float* lin0_w    = (const float*)d_in[2];
    const float* lin0_b    = (const float*)d_in[3];
    const float* nn_w1     = (const float*)d_in[4];
    const float* nn_b1     = (const float*)d_in[5];
    const float* nn_w2     = (const float*)d_in[6];
    const float* nn_b2     = (const float*)d_in[7];
    const float* conv_root = (const float*)d_in[8];
    const float* conv_bias = (const float*)d_in[9];
    const float* gru_w_ih  = (const float*)d_in[10];
    const float* gru_w_hh  = (const float*)d_in[11];
    const float* gru_b_ih  = (const float*)d_in[12];
    const float* gru_b_hh  = (const float*)d_in[13];
    const float* lstm_w_ih = (const float*)d_in[14];
    const float* lstm_w_hh = (const float*)d_in[15];
    const float* lstm_b_ih = (const float*)d_in[16];
    const float* lstm_b_hh = (const float*)d_in[17];
    const float* lin1_w    = (const float*)d_in[18];
    const float* lin1_b    = (const float*)d_in[19];
    const float* lin2_w    = (const float*)d_in[20];
    const float* lin2_b    = (const float*)d_in[21];
    const int*   edge_index= (const int*)d_in[22];
    const int*   batch     = (const int*)d_in[23];
    float* yout = (float*)d_out;

    char* p = (char*)d_ws;
    auto alloc = [&](size_t bytes) { char* r = p; p += (bytes + 255) & ~(size_t)255; return r; };

    // ---- zero region (one memset) ----
    int*   cursor = (int*)  alloc(NN * sizeof(int));
    size_t zero_bytes = (size_t)(p - (char*)d_ws);
    // ---- rest ----
    int*   gstart    = (int*)  alloc((NG + 1) * sizeof(int));
    int*   srt_src   = (int*)  alloc((size_t)NN * CAP * sizeof(int));
    float* srt_ea    = (float*)alloc((size_t)NN * CAP * 2 * sizeof(float));
    float* outA      = (float*)alloc(NN * DIM * sizeof(float));
    float* outB      = (float*)alloc(NN * DIM * sizeof(float));
    float* Sg        = (float*)alloc(NN * DIM * sizeof(float));
    unsigned short* w2f = (unsigned short*)alloc(262144 * sizeof(unsigned short));
    float* ebuf      = (float*)alloc(NN * sizeof(float));
    (void)ws_size; (void)n_in; (void)in_sizes; (void)out_size;

    hipMemsetAsync(d_ws, 0, zero_bytes, stream);

    k_setup<<<2388, 256, 0, stream>>>(nn_w2, w2f, x, lin0_w, lin0_b, outA, batch, gstart,
                                      edge_index, edge_attr, cursor, srt_src, srt_ea);

    const float* cur = outA;
    float* nxt = outB;
    for (int it = 0; it < 3; ++it) {
        k_conv_gru<<<2500, 512, 0, stream>>>(cursor, srt_src, srt_ea,
                                             nn_w1, nn_b1, w2f, nn_b2,
                                             cur, Sg,
                                             conv_root, conv_bias,
                                             gru_w_ih, gru_w_hh, gru_b_ih, gru_b_hh,
                                             nxt);
        const float* tmp = nxt; nxt = (float*)cur; cur = tmp;
    }
    const float* outF = cur;

    k_set2set<<<NG, 256, 0, stream>>>(outF, gstart,
                                      lstm_w_ih, lstm_w_hh, lstm_b_ih, lstm_b_hh,
                                      lin1_w, lin1_b, lin2_w, lin2_b, ebuf, yout);
}

// Round 20
// 328.022 us; speedup vs baseline: 1.1723x; 1.1723x over previous
//
#include <hip/hip_runtime.h>
#include <math.h>

#define NN 10000
#define NE 160000
#define NG 64
#define DIM 32
#define CAP 96   // per-node edge slot capacity (max degree ~40 at Binomial(160K,1e-4))

typedef __attribute__((ext_vector_type(8))) short bf16x8;
typedef __attribute__((ext_vector_type(4))) float f32x4;

__device__ __forceinline__ float sigmoidf_(float x) { return 1.f / (1.f + expf(-x)); }

// round-to-nearest-even fp32 -> bf16 bits
__device__ __forceinline__ unsigned short f2bf(float x) {
    unsigned u = __float_as_uint(x);
    u += 0x7FFF + ((u >> 16) & 1);
    return (unsigned short)(u >> 16);
}
__device__ __forceinline__ float bf2f(unsigned short b) {
    return __uint_as_float(((unsigned)b) << 16);
}

// ---------------------------------------------------------------- fused setup + fill
//   b<512:        W2 -> B-fragment bf16 hi/lo planes (linear w2 read, coalesced)
//   b<1762:       lin0 + relu
//   b==1762:      gstart binary search
//   b>=1763:      direct-slot edge bucketing (625 blocks)
__global__ void k_setup(const float* __restrict__ w2, unsigned short* __restrict__ w2f,
                        const float* __restrict__ x, const float* __restrict__ lw,
                        const float* __restrict__ lb, float* __restrict__ out,
                        const int* __restrict__ batch, int* __restrict__ gstart,
                        const int* __restrict__ ei, const float* __restrict__ ea,
                        int* __restrict__ cursor,
                        int* __restrict__ srt_src, float* __restrict__ srt_ea) {
    int b = blockIdx.x, t = threadIdx.x;
    if (b < 512) {
        int tid = b * 256 + t;                        // linear w2 index (coalesced)
        int h = tid >> 10, rem = tid & 1023, i = rem >> 5, n = rem & 31;
        float v = w2[tid];
        unsigned short hi = f2bf(v);
        unsigned short lo = f2bf(v - bf2f(hi));
        int s = h >> 5, hm = h & 31, q = hm >> 3, j = hm & 7;
        int tile = n >> 4, nn = n & 15, lane = q * 16 + nn;
        int c = (i * 4 + s) * 2 + tile;
        w2f[(c * 2 + 0) * 512 + lane * 8 + j] = hi;
        w2f[(c * 2 + 1) * 512 + lane * 8 + j] = lo;
    } else if (b < 1762) {
        int idx = (b - 512) * 256 + t;               // < NN*DIM
        int n = idx >> 5, d = idx & 31;
        out[idx] = fmaxf(x[n] * lw[d] + lb[d], 0.f);
    } else if (b == 1762) {
        if (t <= NG) {
            int g = t, lo = 0, hi = NN;
            while (lo < hi) { int mid = (lo + hi) >> 1; if (batch[mid] < g) lo = mid + 1; else hi = mid; }
            gstart[g] = lo;
        }
    } else {
        int e = (b - 1763) * 256 + t;
        if (e < NE) {
            int d = ei[NE + e];
            int p = atomicAdd(&cursor[d], 1);
            int pos = d * CAP + p;
            srt_src[pos] = ei[e];
            srt_ea[2 * pos]     = ea[2 * e];
            srt_ea[2 * pos + 1] = ea[2 * e + 1];
        }
    }
}

// ---------------------------------------------------------------- NNConv + GRU fused
// R13/R17 structure (spill-free measured optimum). Edge phase: wave-uniform src
// -> scalar row loads, 2 independent chains (MLP=2; MLP=3 neutral — R16;
// h-split regresses — R5/R19; persistent buffers spill — R8/R11/R15).
// Slots at n*CAP, degree from cursor[n]. Contraction via MFMA 16x16x32 bf16,
// bf16x3 split precision (hh+hl+lh).
#define NS 1040
#define PS 8320
__global__ __launch_bounds__(512, 4) void k_conv_gru(
    const int* __restrict__ cursor, const int* __restrict__ srt_src,
    const float* __restrict__ srt_ea,
    const float* __restrict__ w1, const float* __restrict__ b1,
    const unsigned short* __restrict__ w2f, const float* __restrict__ b2,
    const float* __restrict__ out_old,
    float* __restrict__ Sg,
    const float* __restrict__ root, const float* __restrict__ cbias,
    const float* __restrict__ wih, const float* __restrict__ whh,
    const float* __restrict__ bih, const float* __restrict__ bhh,
    float* __restrict__ out_new)
{
    __shared__ __align__(16) unsigned short RB[2 * PS];   // hi plane + lo plane
    int t = threadIdx.x;
    int wave = t >> 6, lane = t & 63;
    int n0 = blockIdx.x * 8;
    int n = n0 + wave;

    // ---------------- edge phase (2 independent chains per iteration) ----------------
    float Racc[64];
    #pragma unroll
    for (int i = 0; i < 64; ++i) Racc[i] = 0.f;
    float sacc = 0.f;

    float w1a0 = w1[lane],      w1c0 = w1[128 + lane],  bb0 = b1[lane];
    float w1a1 = w1[64 + lane], w1c1 = w1[192 + lane],  bb1 = b1[64 + lane];

    int rs = n * CAP;
    int re = rs + cursor[n];
    const float2* eap = (const float2*)srt_ea;

    int p = rs;
    for (; p + 1 < re; p += 2) {
        int s0 = __builtin_amdgcn_readfirstlane(srt_src[p]);
        int s1 = __builtin_amdgcn_readfirstlane(srt_src[p + 1]);
        float2 a0 = eap[p];
        float2 a1 = eap[p + 1];
        const float* o0 = out_old + s0 * DIM;     // uniform -> s_load
        const float* o1 = out_old + s1 * DIM;     // independent chain
        float r00 = fmaxf(a0.x * w1a0 + a0.y * w1c0 + bb0, 0.f);
        float r01 = fmaxf(a0.x * w1a1 + a0.y * w1c1 + bb1, 0.f);
        float r10 = fmaxf(a1.x * w1a0 + a1.y * w1c0 + bb0, 0.f);
        float r11 = fmaxf(a1.x * w1a1 + a1.y * w1c1 + bb1, 0.f);
        #pragma unroll
        for (int q = 0; q < 32; ++q) {
            float v0 = o0[q];
            Racc[q]      += r00 * v0;
            Racc[32 + q] += r01 * v0;
        }
        #pragma unroll
        for (int q = 0; q < 32; ++q) {
            float v1 = o1[q];
            Racc[q]      += r10 * v1;
            Racc[32 + q] += r11 * v1;
        }
        if (lane < DIM) sacc += o0[lane] + o1[lane];
    }
    if (p < re) {                                  // tail edge
        int s0 = __builtin_amdgcn_readfirstlane(srt_src[p]);
        float2 a0 = eap[p];
        const float* o0 = out_old + s0 * DIM;
        float r00 = fmaxf(a0.x * w1a0 + a0.y * w1c0 + bb0, 0.f);
        float r01 = fmaxf(a0.x * w1a1 + a0.y * w1c1 + bb1, 0.f);
        #pragma unroll
        for (int q = 0; q < 32; ++q) {
            float v0 = o0[q];
            Racc[q]      += r00 * v0;
            Racc[32 + q] += r01 * v0;
        }
        if (lane < DIM) sacc += o0[lane];
    }
    if (lane < DIM) Sg[n * DIM + lane] = sacc;

    // ---------------- MFMA contraction: 4 i-passes of 8 ----------------
    int quad = lane >> 4;
    int mm = lane & 7;                  // A rows 8..15 dup of 0..7 (unread in D)
    unsigned aoff = (unsigned)(mm * NS + wave * 128 + quad * 8);
    f32x4 acc0 = {0.f, 0.f, 0.f, 0.f};
    f32x4 acc1 = {0.f, 0.f, 0.f, 0.f};

    unsigned short* Hw = RB + wave * NS;
    unsigned short* Lw = RB + PS + wave * NS;

    #pragma unroll
    for (int pass = 0; pass < 4; ++pass) {
        if (pass) __syncthreads();                 // prior pass's reads done
        #pragma unroll
        for (int li = 0; li < 8; ++li) {
            float v0 = Racc[pass * 8 + li];        // h = lane
            float v1 = Racc[32 + pass * 8 + li];   // h = lane+64
            unsigned short h0 = f2bf(v0);
            unsigned short l0 = f2bf(v0 - bf2f(h0));
            unsigned short h1 = f2bf(v1);
            unsigned short l1 = f2bf(v1 - bf2f(h1));
            Hw[li * 128 + lane] = h0;  Hw[li * 128 + 64 + lane] = h1;
            Lw[li * 128 + lane] = l0;  Lw[li * 128 + 64 + lane] = l1;
        }
        __syncthreads();
        int ig = pass * 8 + wave;                  // global i-row this wave covers
        #pragma unroll
        for (int s = 0; s < 4; ++s) {
            bf16x8 ah = *(const bf16x8*)(RB + aoff + s * 32);
            bf16x8 al = *(const bf16x8*)(RB + PS + aoff + s * 32);
            const unsigned short* bp = w2f + (unsigned)((ig * 4 + s) * 2048 + lane * 8);
            bf16x8 bh0 = *(const bf16x8*)(bp);
            bf16x8 bl0 = *(const bf16x8*)(bp + 512);
            bf16x8 bh1 = *(const bf16x8*)(bp + 1024);
            bf16x8 bl1 = *(const bf16x8*)(bp + 1536);
            acc0 = __builtin_amdgcn_mfma_f32_16x16x32_bf16(ah, bh0, acc0, 0, 0, 0);
            acc0 = __builtin_amdgcn_mfma_f32_16x16x32_bf16(ah, bl0, acc0, 0, 0, 0);
            acc0 = __builtin_amdgcn_mfma_f32_16x16x32_bf16(al, bh0, acc0, 0, 0, 0);
            acc1 = __builtin_amdgcn_mfma_f32_16x16x32_bf16(ah, bh1, acc1, 0, 0, 0);
            acc1 = __builtin_amdgcn_mfma_f32_16x16x32_bf16(ah, bl1, acc1, 0, 0, 0);
            acc1 = __builtin_amdgcn_mfma_f32_16x16x32_bf16(al, bh1, acc1, 0, 0, 0);
        }
    }
    __syncthreads();                               // all RB reads complete

    // ---- K-partial reduction through LDS (reuse RB as float area) ----
    float* part = (float*)RB;                      // 16 tiles x 64 lanes x 4 = 16 KB
    #pragma unroll
    for (int r = 0; r < 4; ++r) {
        part[((wave * 2 + 0) * 64 + lane) * 4 + r] = acc0[r];
        part[((wave * 2 + 1) * 64 + lane) * 4 + r] = acc1[r];
    }
    __syncthreads();

    // ---------------- fused GRU epilogue (threads 0..255: 8 nodes x 32 dims) ----------------
    if (t < 256) {
        int nb = t >> 5, d = t & 31;
        int nn_ = n0 + nb;
        int base = t & 32;                          // shfl base within wave
        // C/D layout: row=(lane>>4)*4+reg, col=lane&15 -> gather this (nb,d)
        int tile = d >> 4, col = d & 15;
        int lidx = (nb >> 2) * 16 + col, reg = nb & 3;
        float aggv = 0.f;
        #pragma unroll
        for (int wv = 0; wv < 8; ++wv)
            aggv += part[((wv * 2 + tile) * 64 + lidx) * 4 + reg];

        float bt = 0.f;
        #pragma unroll 8
        for (int i = 0; i < DIM; ++i) bt += Sg[nn_ * DIM + i] * b2[i * DIM + d];
        int cdeg = cursor[nn_];
        float degf = (float)(cdeg > 0 ? cdeg : 1);
        aggv = (aggv + bt) / degf;

        float x = out_old[nn_ * DIM + d];           // h_old[d]
        float rootsum = 0.f;
        #pragma unroll 8
        for (int k = 0; k < DIM; ++k)
            rootsum += __shfl(x, base + k) * root[k * DIM + d];
        float m = fmaxf(aggv + rootsum + cbias[d], 0.f);

        float gir = bih[d], giz = bih[DIM + d], gin = bih[2 * DIM + d];
        float ghr = bhh[d], ghz = bhh[DIM + d], ghn = bhh[2 * DIM + d];
        #pragma unroll 4
        for (int k = 0; k < DIM; ++k) {
            float mk = __shfl(m, base + k);
            float hk = __shfl(x, base + k);
            gir += mk * wih[k * 96 + d];
            giz += mk * wih[k * 96 + DIM + d];
            gin += mk * wih[k * 96 + 2 * DIM + d];
            ghr += hk * whh[k * 96 + d];
            ghz += hk * whh[k * 96 + DIM + d];
            ghn += hk * whh[k * 96 + 2 * DIM + d];
        }
        float rg = sigmoidf_(gir + ghr);
        float zg = sigmoidf_(giz + ghz);
        float ng = tanhf(gin + rg * ghn);
        out_new[nn_ * DIM + d] = (1.f - zg) * ng + zg * x;
    }
}

// ---------------------------------------------------------------- Set2Set + head
__global__ __launch_bounds__(256) void k_set2set(
    const float* __restrict__ out, const int* __restrict__ gstart,
    const float* __restrict__ wih, const float* __restrict__ whh,
    const float* __restrict__ bih, const float* __restrict__ bhh,
    const float* __restrict__ l1w, const float* __restrict__ l1b,
    const float* __restrict__ l2w, const float* __restrict__ l2b,
    float* __restrict__ ebuf, float* __restrict__ y)
{
    __shared__ float swih[64 * 128];   // 32 KB
    __shared__ float swhh[32 * 128];   // 16 KB
    __shared__ float sq[2 * DIM];
    __shared__ float shh[DIM], scc[DIM];
    __shared__ float sgates[4 * DIM];
    __shared__ float sacc[8][DIM];
    __shared__ float sredA[4], sredB[4];

    int g = blockIdx.x, t = threadIdx.x;
    {
        const float4* wv = (const float4*)wih;   float4* sv = (float4*)swih;
        for (int i = t; i < 2048; i += 256) sv[i] = wv[i];
        const float4* wv2 = (const float4*)whh;  float4* sv2 = (float4*)swhh;
        for (int i = t; i < 1024; i += 256) sv2[i] = wv2[i];
    }
    if (t < 2 * DIM) sq[t] = 0.f;
    if (t < DIM) { shh[t] = 0.f; scc[t] = 0.f; }
    int ns = gstart[g], ne = gstart[g + 1];
    __syncthreads();

    for (int step = 0; step < 3; ++step) {
        if (t < 128) {
            float acc = bih[t] + bhh[t];
            #pragma unroll 8
            for (int k = 0; k < 2 * DIM; ++k) acc += sq[k] * swih[k * 128 + t];
            #pragma unroll 8
            for (int k = 0; k < DIM; ++k)     acc += shh[k] * swhh[k * 128 + t];
            sgates[t] = acc;
        }
        __syncthreads();
        if (t < DIM) {
            float ig = sigmoidf_(sgates[t]);
            float fg = sigmoidf_(sgates[DIM + t]);
            float gg = tanhf(sgates[2 * DIM + t]);
            float og = sigmoidf_(sgates[3 * DIM + t]);
            float c_new = fg * scc[t] + ig * gg;
            float h_new = og * tanhf(c_new);
            scc[t] = c_new;
            shh[t] = h_new;
            sq[t] = h_new;
        }
        __syncthreads();

        float lmax = -3.0e38f;
        for (int n = ns + t; n < ne; n += 256) {
            const float4* orow = (const float4*)(out + n * DIM);
            float e = 0.f;
            #pragma unroll
            for (int q = 0; q < 8; ++q) {
                float4 o4 = orow[q];
                e += o4.x * shh[4 * q] + o4.y * shh[4 * q + 1]
                   + o4.z * shh[4 * q + 2] + o4.w * shh[4 * q + 3];
            }
            ebuf[n] = e;
            lmax = fmaxf(lmax, e);
        }
        #pragma unroll
        for (int s = 1; s < 64; s <<= 1) lmax = fmaxf(lmax, __shfl_xor(lmax, s));
        if ((t & 63) == 0) sredA[t >> 6] = lmax;
        __syncthreads();
        float M = fmaxf(fmaxf(sredA[0], sredA[1]), fmaxf(sredA[2], sredA[3]));

        float lsum = 0.f;
        for (int n = ns + t; n < ne; n += 256) {
            float v = expf(ebuf[n] - M);
            ebuf[n] = v;
            lsum += v;
        }
        #pragma unroll
        for (int s = 1; s < 64; s <<= 1) lsum += __shfl_xor(lsum, s);
        if ((t & 63) == 0) sredB[t >> 6] = lsum;
        __syncthreads();
        float S = sredB[0] + sredB[1] + sredB[2] + sredB[3];
        float inv = (S > 0.f) ? 1.f / S : 0.f;

        int stp = t >> 5, d = t & 31;
        float racc = 0.f;
        for (int n = ns + stp; n < ne; n += 8)
            racc += ebuf[n] * out[n * DIM + d];
        sacc[stp][d] = racc;
        __syncthreads();
        if (t < DIM) {
            float r = 0.f;
            #pragma unroll
            for (int s = 0; s < 8; ++s) r += sacc[s][t];
            sq[DIM + t] = r * inv;
        }
        __syncthreads();
    }

    if (t < DIM) {
        float h = l1b[t];
        #pragma unroll 8
        for (int k = 0; k < 2 * DIM; ++k) h += sq[k] * l1w[k * DIM + t];
        float v = fmaxf(h, 0.f) * l2w[t];
        #pragma unroll
        for (int s = 1; s < 32; s <<= 1) v += __shfl_xor(v, s);
        if (t == 0) y[g] = v + l2b[0];
    }
}

// ---------------------------------------------------------------- launch
extern "C" void kernel_launch(void* const* d_in, const int* in_sizes, int n_in,
                              void* d_out, int out_size, void* d_ws, size_t ws_size,
                              hipStream_t stream) {
    const float* x         = (const float*)d_in[0];
    const float* edge_attr = (const float*)d_in[1];
    const float* lin0_w    = (const float*)d_in[2];
    const float* lin0_b    = (const float*)d_in[3];
    const float* nn_w1     = (const float*)d_in[4];
    const float* nn_b1     = (const float*)d_in[5];
    const float* nn_w2     = (const float*)d_in[6];
    const float* nn_b2     = (const float*)d_in[7];
    const float* conv_root = (const float*)d_in[8];
    const float* conv_bias = (const float*)d_in[9];
    const float* gru_w_ih  = (const float*)d_in[10];
    const float* gru_w_hh  = (const float*)d_in[11];
    const float* gru_b_ih  = (const float*)d_in[12];
    const float* gru_b_hh  = (const float*)d_in[13];
    const float* lstm_w_ih = (const float*)d_in[14];
    const float* lstm_w_hh = (const float*)d_in[15];
    const float* lstm_b_ih = (const float*)d_in[16];
    const float* lstm_b_hh = (const float*)d_in[17];
    const float* lin1_w    = (const float*)d_in[18];
    const float* lin1_b    = (const float*)d_in[19];
    const float* lin2_w    = (const float*)d_in[20];
    const float* lin2_b    = (const float*)d_in[21];
    const int*   edge_index= (const int*)d_in[22];
    const int*   batch     = (const int*)d_in[23];
    float* yout = (float*)d_out;

    char* p = (char*)d_ws;
    auto alloc = [&](size_t bytes) { char* r = p; p += (bytes + 255) & ~(size_t)255; return r; };

    // ---- zero region (one memset) ----
    int*   cursor = (int*)  alloc(NN * sizeof(int));
    size_t zero_bytes = (size_t)(p - (char*)d_ws);
    // ---- rest ----
    int*   gstart    = (int*)  alloc((NG + 1) * sizeof(int));
    int*   srt_src   = (int*)  alloc((size_t)NN * CAP * sizeof(int));
    float* srt_ea    = (float*)alloc((size_t)NN * CAP * 2 * sizeof(float));
    float* outA      = (float*)alloc(NN * DIM * sizeof(float));
    float* outB      = (float*)alloc(NN * DIM * sizeof(float));
    float* Sg        = (float*)alloc(NN * DIM * sizeof(float));
    unsigned short* w2f = (unsigned short*)alloc(262144 * sizeof(unsigned short));
    float* ebuf      = (float*)alloc(NN * sizeof(float));
    (void)ws_size; (void)n_in; (void)in_sizes; (void)out_size;

    hipMemsetAsync(d_ws, 0, zero_bytes, stream);

    k_setup<<<2388, 256, 0, stream>>>(nn_w2, w2f, x, lin0_w, lin0_b, outA, batch, gstart,
                                      edge_index, edge_attr, cursor, srt_src, srt_ea);

    const float* cur = outA;
    float* nxt = outB;
    for (int it = 0; it < 3; ++it) {
        k_conv_gru<<<1250, 512, 0, stream>>>(cursor, srt_src, srt_ea,
                                             nn_w1, nn_b1, w2f, nn_b2,
                                             cur, Sg,
                                             conv_root, conv_bias,
                                             gru_w_ih, gru_w_hh, gru_b_ih, gru_b_hh,
                                             nxt);
        const float* tmp = nxt; nxt = (float*)cur; cur = tmp;
    }
    const float* outF = cur;

    k_set2set<<<NG, 256, 0, stream>>>(outF, gstart,
                                      lstm_w_ih, lstm_w_hh, lstm_b_ih, lstm_b_hh,
                                      lin1_w, lin1_b, lin2_w, lin2_b, ebuf, yout);
}